// Round 18
// baseline (77.209 us; speedup 1.0000x reference)
//
#include <hip/hip_runtime.h>
#include <cstdint>

#define DEG 16
#define NNODE 100000
#define NTILE 3125
#define NT64 1563

typedef _Float16 f16;
typedef _Float16 h2v  __attribute__((ext_vector_type(2)));
typedef _Float16 f16x8 __attribute__((ext_vector_type(8)));
typedef float    f32x4 __attribute__((ext_vector_type(4)));

union U4 { uint4 u; h2v h[4]; f16x8 v; };
union U1 { uint32_t i; h2v h; };

__device__ __forceinline__ h2v pk2h(float a, float b) {
    auto r = __builtin_amdgcn_cvt_pkrtz(a, b);   // __fp16 ext_vector(2)
    h2v o;
    __builtin_memcpy(&o, &r, sizeof(o));
    return o;
}

// K-permutation (involution): swap bit-fields [2:3] and [4:5] of a 0..127 index.
__device__ __host__ __forceinline__ int kperm(int p) {
    return (p & 0xC3) | ((p & 0x0C) << 2) | ((p & 0x30) >> 2);
}

// ---------------- k_prep ----------------
// W1A[mt(16)][kb(2)][lane(64)][j(8)] : element Acomb[m][k], m=16*mt+(lane&15), k=kb*32+(lane>>4)*8+j
//   Acomb[m][k] = (m<128) ? W1[k][m] : W1[64+k][m-128]      (k = y-feature dim, NOT permuted)
// W2A[mt(4)][kb(4)][lane(64)][j(8)]  : element W2[kperm(p)][c], p=kb*32+(lane>>4)*8+j, c=16*mt+(lane&15)
__global__ __launch_bounds__(256) void k_prep(
    const float* __restrict__ W1, const float* __restrict__ W2,
    f16* __restrict__ W1A, f16* __restrict__ W2A)
{
    const int g0 = blockIdx.x * 256 + threadIdx.x;
    for (int i = g0; i < 16384 + 8192; i += 24 * 256) {
        if (i < 16384) {
            const int j = i & 7, lane = (i >> 3) & 63, kb = (i >> 9) & 1, mt = i >> 10;
            const int m = 16 * mt + (lane & 15);
            const int k = kb * 32 + (lane >> 4) * 8 + j;
            const int row = (m < 128) ? k : (64 + k);
            const int col = m & 127;
            W1A[i] = (f16)W1[row * 128 + col];
        } else {
            const int ii = i - 16384;
            const int j = ii & 7, lane = (ii >> 3) & 63, kb = (ii >> 9) & 3, mt = ii >> 11;
            const int c = 16 * mt + (lane & 15);
            const int p = kb * 32 + (lane >> 4) * 8 + j;
            W2A[ii] = (f16)W2[kperm(p) * 64 + c];
        }
    }
}

// ---------------- k_uv: swapped-operand MFMA GEMM over 64 nodes/block, LDS-staged y ----------------
// U stored fp8 e4m3 (128 B/row, permuted cols); V stored fp16 (+b1, 256 B/row, permuted cols).
__global__ __launch_bounds__(256, 4) void k_uv(
    const float* __restrict__ y, const f16* __restrict__ W1A,
    const float* __restrict__ b1,
    unsigned char* __restrict__ U8, f16* __restrict__ Vh, float2* __restrict__ QN)
{
    __shared__ float ysh[4096];   // 64 rows x 64 f32 = 16 KB, XOR-swizzled rows
    const int t = threadIdx.x;
    const long nbase = (long)blockIdx.x * 64;
    const int lane = t & 63;
    const int w = t >> 6;
    const int c16 = lane & 15, q = lane >> 4;

    // coalesced stage of the 64-node y tile (clamped for the tail block)
    {
        const size_t max4 = (size_t)NNODE * 16;
        char* yb = (char*)ysh;
        #pragma unroll
        for (int i = 0; i < 4; ++i) {
            const int e = t + i * 256;                 // float4 slot 0..1023
            size_t gidx = (size_t)blockIdx.x * 1024 + e;
            if (gidx >= max4) gidx = max4 - 1;
            const float4 v = ((const float4*)y)[gidx];
            const int B = e * 16;
            const int row = B >> 8;
            *(float4*)(yb + (B ^ ((row & 7) << 4))) = v;
        }
    }

    if (QN != nullptr && t < 64) {
        const long node = nbase + t;
        if (node < NNODE) {
            const float qx = y[node * 64], qy = y[node * 64 + 1];
            const float n = fmaxf(sqrtf(qx * qx + qy * qy), 1e-9f);
            QN[node] = make_float2(qx / n, qy / n);
        }
    }
    __syncthreads();

    // B-fragments from LDS (col = node, k = feature), 4 node-tiles
    const char* yb = (const char*)ysh;
    f16x8 bf[4][2];
    #pragma unroll
    for (int nt = 0; nt < 4; ++nt) {
        const int r = 16 * nt + c16;
        const int sw = (r & 7) << 4;
        #pragma unroll
        for (int kb = 0; kb < 2; ++kb) {
            const int base = r * 256 + kb * 128 + q * 32;
            const float4 a = *(const float4*)(yb + (base ^ sw));
            const float4 b = *(const float4*)(yb + ((base + 16) ^ sw));
            U4 rg;
            rg.h[0] = pk2h(a.x, a.y);
            rg.h[1] = pk2h(a.z, a.w);
            rg.h[2] = pk2h(b.x, b.y);
            rg.h[3] = pk2h(b.z, b.w);
            bf[nt][kb] = rg.v;
        }
    }

    f32x4 acc[4][4];
    #pragma unroll
    for (int i = 0; i < 4; ++i)
        #pragma unroll
        for (int nt = 0; nt < 4; ++nt)
            acc[i][nt] = (f32x4){0.f, 0.f, 0.f, 0.f};

    #pragma unroll
    for (int i = 0; i < 4; ++i) {
        const int mt = 4 * w + i;
        #pragma unroll
        for (int kb = 0; kb < 2; ++kb) {
            const f16x8 af = *(const f16x8*)&W1A[((mt * 2 + kb) * 64 + lane) * 8];
            #pragma unroll
            for (int nt = 0; nt < 4; ++nt)
                acc[i][nt] = __builtin_amdgcn_mfma_f32_16x16x32_f16(af, bf[nt][kb], acc[i][nt], 0, 0, 0);
        }
    }

    // epilogue: lane (w,q,c16) holds true cols {16*(4w+i)+4q+r}; permuted positions
    // 64*(w&1)+16*q+4*i+r are contiguous -> U: 16 fp8 bytes; V: 16 f16 (32 B).
    const bool isV = (w >= 2);
    const int wef = w & 1;
    float4 b1v[4];
    #pragma unroll
    for (int i = 0; i < 4; ++i) b1v[i] = make_float4(0.f, 0.f, 0.f, 0.f);
    if (isV) {
        #pragma unroll
        for (int i = 0; i < 4; ++i)
            b1v[i] = *(const float4*)&b1[wef * 64 + 16 * i + 4 * q];
    }

    #pragma unroll
    for (int nt = 0; nt < 4; ++nt) {
        const long node = nbase + 16 * nt + c16;
        if (node >= NNODE) continue;
        if (!isV) {
            uint4 pkt;
            uint32_t wd[4];
            #pragma unroll
            for (int i = 0; i < 4; ++i) {
                uint32_t v0 = __builtin_amdgcn_cvt_pk_fp8_f32(acc[i][nt][0], acc[i][nt][1], 0, false);
                wd[i] = __builtin_amdgcn_cvt_pk_fp8_f32(acc[i][nt][2], acc[i][nt][3], v0, true);
            }
            pkt.x = wd[0]; pkt.y = wd[1]; pkt.z = wd[2]; pkt.w = wd[3];
            *(uint4*)(U8 + node * 128 + wef * 64 + q * 16) = pkt;
        } else {
            f16* dst = Vh + node * 128 + wef * 64 + q * 16;
            U4 p0, p1;
            p0.h[0] = pk2h(acc[0][nt][0] + b1v[0].x, acc[0][nt][1] + b1v[0].y);
            p0.h[1] = pk2h(acc[0][nt][2] + b1v[0].z, acc[0][nt][3] + b1v[0].w);
            p0.h[2] = pk2h(acc[1][nt][0] + b1v[1].x, acc[1][nt][1] + b1v[1].y);
            p0.h[3] = pk2h(acc[1][nt][2] + b1v[1].z, acc[1][nt][3] + b1v[1].w);
            p1.h[0] = pk2h(acc[2][nt][0] + b1v[2].x, acc[2][nt][1] + b1v[2].y);
            p1.h[1] = pk2h(acc[2][nt][2] + b1v[2].z, acc[2][nt][3] + b1v[2].w);
            p1.h[2] = pk2h(acc[3][nt][0] + b1v[3].x, acc[3][nt][1] + b1v[3].y);
            p1.h[3] = pk2h(acc[3][nt][2] + b1v[3].z, acc[3][nt][3] + b1v[3].w);
            *(uint4*)dst       = p0.u;
            *(uint4*)(dst + 8) = p1.u;
        }
    }
}

// ---------------- k_agg: softmax + wide (16 B/lane) fp8 gather + swapped MFMA epilogue ----------------
// 8 lanes per U row (uint4/lane): 8 edges per load instruction, U load count halved.
template<bool USE_QN>
__global__ __launch_bounds__(256, 6) void k_agg(
    const float* __restrict__ y, const int* __restrict__ idx,
    const unsigned char* __restrict__ U8, const f16* __restrict__ Vh,
    const float2* __restrict__ QN, const f16* __restrict__ W2A,
    const float* __restrict__ b2, float* __restrict__ out)
{
    __shared__ uint32_t accs[2048];   // 32 x 128 f16, XOR-swizzled (8 KB)

    const int t = threadIdx.x, lane = t & 63, wave = t >> 6;
    const int c16 = lane & 15, quarter = lane >> 4;
    const int G = lane >> 3;          // 0..7 edge-group
    const int c8 = lane & 7;          // col-block (16 fp8 / 16 f16) within row
    const int nodeBase = blockIdx.x * 32 + wave * 8;

    int jA[8];
    #pragma unroll
    for (int g = 0; g < 8; ++g)
        jA[g] = idx[(nodeBase + g) * DEG + c16];

    // ---- scores + segment softmax (16-lane groups, replicated across quarters) ----
    float aA[8];
    #pragma unroll
    for (int g = 0; g < 8; ++g) {
        const int i = nodeBase + g;
        float s;
        if (USE_QN) {
            const float2 qn = QN[i];
            const float2 kn = QN[jA[g]];
            s = qn.x * kn.x + qn.y * kn.y;
        } else {
            const float2 qv = *(const float2*)&y[(long)i * 64];
            const float2 kv = *(const float2*)&y[(long)jA[g] * 64];
            const float nq = fmaxf(sqrtf(qv.x * qv.x + qv.y * qv.y), 1e-9f);
            const float nk = fmaxf(sqrtf(kv.x * kv.x + kv.y * kv.y), 1e-9f);
            s = (qv.x * kv.x + qv.y * kv.y) / (nq * nk);
        }
        float m = s;
        #pragma unroll
        for (int d = 1; d < 16; d <<= 1) m = fmaxf(m, __shfl_xor(m, d));
        const float ex = __expf(s - m);
        float sum = ex;
        #pragma unroll
        for (int d = 1; d < 16; d <<= 1) sum += __shfl_xor(sum, d);
        aA[g] = ex / sum;
    }

    // ---- gather/accumulate: double buffer; U row = 8 lanes x uint4; V row = 2 uint4/lane ----
    const uint4* Uv = (const uint4*)U8;   // row = 8 uint4
    const uint4* Vv = (const uint4*)Vh;   // row = 16 uint4
    char* accb = (char*)accs;

    uint4 ub[2][2], vb[2][2];
    #pragma unroll
    for (int ee = 0; ee < 2; ++ee) {
        const long je = __shfl(jA[0], 8 * ee + G);
        ub[0][ee] = Uv[je * 8 + c8];
    }
    vb[0][0] = Vv[(long)nodeBase * 16 + c8 * 2];
    vb[0][1] = Vv[(long)nodeBase * 16 + c8 * 2 + 1];

    #pragma unroll
    for (int g = 0; g < 8; ++g) {
        const int cur = g & 1, nx = cur ^ 1;
        if (g < 7) {
            #pragma unroll
            for (int ee = 0; ee < 2; ++ee) {
                const long je = __shfl(jA[g + 1], 8 * ee + G);
                ub[nx][ee] = Uv[je * 8 + c8];
            }
            vb[nx][0] = Vv[(long)(nodeBase + g + 1) * 16 + c8 * 2];
            vb[nx][1] = Vv[(long)(nodeBase + g + 1) * 16 + c8 * 2 + 1];
        }
        // unpack V (16 f16 = 8 h2v)
        h2v vh[8];
        {
            U4 tv;
            tv.u = vb[cur][0];
            vh[0] = tv.h[0]; vh[1] = tv.h[1]; vh[2] = tv.h[2]; vh[3] = tv.h[3];
            tv.u = vb[cur][1];
            vh[4] = tv.h[0]; vh[5] = tv.h[1]; vh[6] = tv.h[2]; vh[7] = tv.h[3];
        }
        const h2v z2 = {0, 0};
        h2v r[8] = {z2, z2, z2, z2, z2, z2, z2, z2};
        #pragma unroll
        for (int ee = 0; ee < 2; ++ee) {
            const float ae = __shfl(aA[g], 8 * ee + G);
            const h2v az = pk2h(ae, ae);
            const uint4 uu = ub[cur][ee];
            auto p0 = __builtin_amdgcn_cvt_pk_f32_fp8(uu.x, false);
            auto p1 = __builtin_amdgcn_cvt_pk_f32_fp8(uu.x, true);
            auto p2 = __builtin_amdgcn_cvt_pk_f32_fp8(uu.y, false);
            auto p3 = __builtin_amdgcn_cvt_pk_f32_fp8(uu.y, true);
            auto p4 = __builtin_amdgcn_cvt_pk_f32_fp8(uu.z, false);
            auto p5 = __builtin_amdgcn_cvt_pk_f32_fp8(uu.z, true);
            auto p6 = __builtin_amdgcn_cvt_pk_f32_fp8(uu.w, false);
            auto p7 = __builtin_amdgcn_cvt_pk_f32_fp8(uu.w, true);
            const h2v u_[8] = {
                pk2h(p0[0], p0[1]), pk2h(p1[0], p1[1]), pk2h(p2[0], p2[1]), pk2h(p3[0], p3[1]),
                pk2h(p4[0], p4[1]), pk2h(p5[0], p5[1]), pk2h(p6[0], p6[1]), pk2h(p7[0], p7[1])
            };
            #pragma unroll
            for (int k2 = 0; k2 < 8; ++k2)
                r[k2] += __builtin_elementwise_max(u_[k2] + vh[k2], z2) * az;
        }
        // reduce across the 8 edge-groups (xor 8,16,32)
        #pragma unroll
        for (int k2 = 0; k2 < 8; ++k2) {
            U1 v; v.h = r[k2];
            U1 o;
            o.i = __shfl_xor(v.i, 8);  v.h = v.h + o.h;
            o.i = __shfl_xor(v.i, 16); v.h = v.h + o.h;
            o.i = __shfl_xor(v.i, 32); v.h = v.h + o.h;
            r[k2] = v.h;
        }
        if (G == 0) {
            const int rrow = wave * 8 + g;
            const int sw = (rrow & 7) << 4;
            U4 pkA, pkB;
            pkA.h[0] = r[0]; pkA.h[1] = r[1]; pkA.h[2] = r[2]; pkA.h[3] = r[3];
            pkB.h[0] = r[4]; pkB.h[1] = r[5]; pkB.h[2] = r[6]; pkB.h[3] = r[7];
            *(uint4*)(accb + ((rrow * 256 + c8 * 32) ^ sw))      = pkA.u;
            *(uint4*)(accb + ((rrow * 256 + c8 * 32 + 16) ^ sw)) = pkB.u;
        }
    }
    __syncthreads();

    // ---- swapped MFMA epilogue: D[64 W2cols][32 nodes] = W2'^T x ACC^T (both K-permuted) ----
    f16x8 waf[4];
    #pragma unroll
    for (int kb = 0; kb < 4; ++kb)
        waf[kb] = *(const f16x8*)&W2A[((wave * 4 + kb) * 64 + lane) * 8];
    const float4 b2v = *(const float4*)&b2[16 * wave + quarter * 4];

    f32x4 d[2];
    #pragma unroll
    for (int nt = 0; nt < 2; ++nt) d[nt] = (f32x4){0.f, 0.f, 0.f, 0.f};
    #pragma unroll
    for (int nt = 0; nt < 2; ++nt) {
        const int n = 16 * nt + c16;
        const int sw = (n & 7) << 4;
        #pragma unroll
        for (int kb = 0; kb < 4; ++kb) {
            const f16x8 bfr = *(const f16x8*)(accb + ((n * 256 + kb * 64 + quarter * 16) ^ sw));
            d[nt] = __builtin_amdgcn_mfma_f32_16x16x32_f16(waf[kb], bfr, d[nt], 0, 0, 0);
        }
    }
    #pragma unroll
    for (int nt = 0; nt < 2; ++nt) {
        const long node = blockIdx.x * 32 + 16 * nt + c16;
        const int col = 16 * wave + quarter * 4;
        float4 o;
        o.x = d[nt][0] + b2v.x; o.y = d[nt][1] + b2v.y;
        o.z = d[nt][2] + b2v.z; o.w = d[nt][3] + b2v.w;
        *(float4*)&out[node * 64 + col] = o;
    }
}

extern "C" void kernel_launch(void* const* d_in, const int* in_sizes, int n_in,
                              void* d_out, int out_size, void* d_ws, size_t ws_size,
                              hipStream_t stream) {
    const float* y   = (const float*)d_in[0];
    const int*   idx = (const int*)d_in[1];
    // d_in[2] = indptr: uniform DEG=16, unused
    const float* W1  = (const float*)d_in[3];
    const float* b1  = (const float*)d_in[4];
    const float* W2  = (const float*)d_in[5];
    const float* b2  = (const float*)d_in[6];
    float* out = (float*)d_out;

    char* ws = (char*)d_ws;
    unsigned char* U8 = (unsigned char*)ws;                // 12,800,000 B (fp8 e4m3)
    f16* Vh  = (f16*)(ws + 12800000);                      // 25,600,000 B (fp16, +b1)
    f16* W1A = (f16*)(ws + 38400000);                      // 32,768 B
    f16* W2A = (f16*)(ws + 38432768);                      // 16,384 B
    const size_t qn_off = 38449152;
    const bool useQN = (ws_size >= qn_off + (size_t)NNODE * sizeof(float2));
    float2* QN = useQN ? (float2*)(ws + qn_off) : nullptr;

    k_prep<<<24, 256, 0, stream>>>(W1, W2, W1A, W2A);
    k_uv<<<NT64, 256, 0, stream>>>(y, W1A, b1, U8, Vh, QN);
    if (useQN)
        k_agg<true><<<NTILE, 256, 0, stream>>>(y, idx, U8, Vh, QN, W2A, b2, out);
    else
        k_agg<false><<<NTILE, 256, 0, stream>>>(y, idx, U8, Vh, nullptr, W2A, b2, out);
}

// Round 19
// 65.428 us; speedup vs baseline: 1.1801x; 1.1801x over previous
//
#include <hip/hip_runtime.h>
#include <cstdint>

#define DEG 16
#define NNODE 100000
#define NTILE 3125
#define NT64 1563

typedef _Float16 f16;
typedef _Float16 h2v  __attribute__((ext_vector_type(2)));
typedef _Float16 f16x8 __attribute__((ext_vector_type(8)));
typedef float    f32x4 __attribute__((ext_vector_type(4)));

union U4 { uint4 u; h2v h[4]; f16x8 v; };
union U1 { uint32_t i; h2v h; };

__device__ __forceinline__ h2v pk2h(float a, float b) {
    auto r = __builtin_amdgcn_cvt_pkrtz(a, b);   // __fp16 ext_vector(2)
    h2v o;
    __builtin_memcpy(&o, &r, sizeof(o));
    return o;
}

// K-permutation (involution): swap bit-fields [2:3] and [4:5] of a 0..127 index.
__device__ __host__ __forceinline__ int kperm(int p) {
    return (p & 0xC3) | ((p & 0x0C) << 2) | ((p & 0x30) >> 2);
}

// ---------------- k_prep ----------------
// W1A[mt(16)][kb(2)][lane(64)][j(8)] : element Acomb[m][k], m=16*mt+(lane&15), k=kb*32+(lane>>4)*8+j
//   Acomb[m][k] = (m<128) ? W1[k][m] : W1[64+k][m-128]      (k = y-feature dim, NOT permuted)
// W2A[mt(4)][kb(4)][lane(64)][j(8)]  : element W2[kperm(p)][c], p=kb*32+(lane>>4)*8+j, c=16*mt+(lane&15)
__global__ __launch_bounds__(256) void k_prep(
    const float* __restrict__ W1, const float* __restrict__ W2,
    f16* __restrict__ W1A, f16* __restrict__ W2A)
{
    const int g0 = blockIdx.x * 256 + threadIdx.x;
    for (int i = g0; i < 16384 + 8192; i += 24 * 256) {
        if (i < 16384) {
            const int j = i & 7, lane = (i >> 3) & 63, kb = (i >> 9) & 1, mt = i >> 10;
            const int m = 16 * mt + (lane & 15);
            const int k = kb * 32 + (lane >> 4) * 8 + j;
            const int row = (m < 128) ? k : (64 + k);
            const int col = m & 127;
            W1A[i] = (f16)W1[row * 128 + col];
        } else {
            const int ii = i - 16384;
            const int j = ii & 7, lane = (ii >> 3) & 63, kb = (ii >> 9) & 3, mt = ii >> 11;
            const int c = 16 * mt + (lane & 15);
            const int p = kb * 32 + (lane >> 4) * 8 + j;
            W2A[ii] = (f16)W2[kperm(p) * 64 + c];
        }
    }
}

// ---------------- k_uv: swapped-operand MFMA GEMM over 64 nodes/block, LDS-staged y ----------------
// U stored fp8 e4m3 (128 B/row, permuted cols); V stored fp16 (+b1, 256 B/row, permuted cols).
__global__ __launch_bounds__(256, 4) void k_uv(
    const float* __restrict__ y, const f16* __restrict__ W1A,
    const float* __restrict__ b1,
    unsigned char* __restrict__ U8, f16* __restrict__ Vh, float2* __restrict__ QN)
{
    __shared__ float ysh[4096];   // 64 rows x 64 f32 = 16 KB, XOR-swizzled rows
    const int t = threadIdx.x;
    const long nbase = (long)blockIdx.x * 64;
    const int lane = t & 63;
    const int w = t >> 6;
    const int c16 = lane & 15, q = lane >> 4;

    // coalesced stage of the 64-node y tile (clamped for the tail block)
    {
        const size_t max4 = (size_t)NNODE * 16;
        char* yb = (char*)ysh;
        #pragma unroll
        for (int i = 0; i < 4; ++i) {
            const int e = t + i * 256;                 // float4 slot 0..1023
            size_t gidx = (size_t)blockIdx.x * 1024 + e;
            if (gidx >= max4) gidx = max4 - 1;
            const float4 v = ((const float4*)y)[gidx];
            const int B = e * 16;
            const int row = B >> 8;
            *(float4*)(yb + (B ^ ((row & 7) << 4))) = v;
        }
    }

    if (QN != nullptr && t < 64) {
        const long node = nbase + t;
        if (node < NNODE) {
            const float qx = y[node * 64], qy = y[node * 64 + 1];
            const float n = fmaxf(sqrtf(qx * qx + qy * qy), 1e-9f);
            QN[node] = make_float2(qx / n, qy / n);
        }
    }
    __syncthreads();

    // B-fragments from LDS (col = node, k = feature), 4 node-tiles
    const char* yb = (const char*)ysh;
    f16x8 bf[4][2];
    #pragma unroll
    for (int nt = 0; nt < 4; ++nt) {
        const int r = 16 * nt + c16;
        const int sw = (r & 7) << 4;
        #pragma unroll
        for (int kb = 0; kb < 2; ++kb) {
            const int base = r * 256 + kb * 128 + q * 32;
            const float4 a = *(const float4*)(yb + (base ^ sw));
            const float4 b = *(const float4*)(yb + ((base + 16) ^ sw));
            U4 rg;
            rg.h[0] = pk2h(a.x, a.y);
            rg.h[1] = pk2h(a.z, a.w);
            rg.h[2] = pk2h(b.x, b.y);
            rg.h[3] = pk2h(b.z, b.w);
            bf[nt][kb] = rg.v;
        }
    }

    f32x4 acc[4][4];
    #pragma unroll
    for (int i = 0; i < 4; ++i)
        #pragma unroll
        for (int nt = 0; nt < 4; ++nt)
            acc[i][nt] = (f32x4){0.f, 0.f, 0.f, 0.f};

    #pragma unroll
    for (int i = 0; i < 4; ++i) {
        const int mt = 4 * w + i;
        #pragma unroll
        for (int kb = 0; kb < 2; ++kb) {
            const f16x8 af = *(const f16x8*)&W1A[((mt * 2 + kb) * 64 + lane) * 8];
            #pragma unroll
            for (int nt = 0; nt < 4; ++nt)
                acc[i][nt] = __builtin_amdgcn_mfma_f32_16x16x32_f16(af, bf[nt][kb], acc[i][nt], 0, 0, 0);
        }
    }

    // epilogue: lane (w,q,c16) holds true cols {16*(4w+i)+4q+r}; permuted positions
    // 64*(w&1)+16*q+4*i+r are contiguous -> U: 16 fp8 bytes; V: 16 f16 (32 B).
    const bool isV = (w >= 2);
    const int wef = w & 1;
    float4 b1v[4];
    #pragma unroll
    for (int i = 0; i < 4; ++i) b1v[i] = make_float4(0.f, 0.f, 0.f, 0.f);
    if (isV) {
        #pragma unroll
        for (int i = 0; i < 4; ++i)
            b1v[i] = *(const float4*)&b1[wef * 64 + 16 * i + 4 * q];
    }

    #pragma unroll
    for (int nt = 0; nt < 4; ++nt) {
        const long node = nbase + 16 * nt + c16;
        if (node >= NNODE) continue;
        if (!isV) {
            uint4 pkt;
            uint32_t wd[4];
            #pragma unroll
            for (int i = 0; i < 4; ++i) {
                uint32_t v0 = __builtin_amdgcn_cvt_pk_fp8_f32(acc[i][nt][0], acc[i][nt][1], 0, false);
                wd[i] = __builtin_amdgcn_cvt_pk_fp8_f32(acc[i][nt][2], acc[i][nt][3], v0, true);
            }
            pkt.x = wd[0]; pkt.y = wd[1]; pkt.z = wd[2]; pkt.w = wd[3];
            *(uint4*)(U8 + node * 128 + wef * 64 + q * 16) = pkt;
        } else {
            f16* dst = Vh + node * 128 + wef * 64 + q * 16;
            U4 p0, p1;
            p0.h[0] = pk2h(acc[0][nt][0] + b1v[0].x, acc[0][nt][1] + b1v[0].y);
            p0.h[1] = pk2h(acc[0][nt][2] + b1v[0].z, acc[0][nt][3] + b1v[0].w);
            p0.h[2] = pk2h(acc[1][nt][0] + b1v[1].x, acc[1][nt][1] + b1v[1].y);
            p0.h[3] = pk2h(acc[1][nt][2] + b1v[1].z, acc[1][nt][3] + b1v[1].w);
            p1.h[0] = pk2h(acc[2][nt][0] + b1v[2].x, acc[2][nt][1] + b1v[2].y);
            p1.h[1] = pk2h(acc[2][nt][2] + b1v[2].z, acc[2][nt][3] + b1v[2].w);
            p1.h[2] = pk2h(acc[3][nt][0] + b1v[3].x, acc[3][nt][1] + b1v[3].y);
            p1.h[3] = pk2h(acc[3][nt][2] + b1v[3].z, acc[3][nt][3] + b1v[3].w);
            *(uint4*)dst       = p0.u;
            *(uint4*)(dst + 8) = p1.u;
        }
    }
}

// ---------------- k_agg: softmax + double-buffered fp8-U gather + swapped MFMA epilogue ----------------
template<bool USE_QN>
__global__ __launch_bounds__(256, 6) void k_agg(
    const float* __restrict__ y, const int* __restrict__ idx,
    const unsigned char* __restrict__ U8, const f16* __restrict__ Vh,
    const float2* __restrict__ QN, const f16* __restrict__ W2A,
    const float* __restrict__ b2, float* __restrict__ out)
{
    __shared__ uint32_t accs[2048];   // 32 rows x 128 f16 (256 B), XOR-swizzled

    const int t = threadIdx.x, lane = t & 63, wave = t >> 6;
    const int c16 = lane & 15, quarter = lane >> 4;
    const int nodeBase = blockIdx.x * 32 + wave * 8;

    int jA[8];
    #pragma unroll
    for (int g = 0; g < 8; ++g)
        jA[g] = idx[(nodeBase + g) * DEG + c16];

    // ---- scores + segment softmax (16-lane groups, replicated across quarters) ----
    float aA[8];
    #pragma unroll
    for (int g = 0; g < 8; ++g) {
        const int i = nodeBase + g;
        float s;
        if (USE_QN) {
            const float2 qn = QN[i];
            const float2 kn = QN[jA[g]];
            s = qn.x * kn.x + qn.y * kn.y;
        } else {
            const float2 qv = *(const float2*)&y[(long)i * 64];
            const float2 kv = *(const float2*)&y[(long)jA[g] * 64];
            const float nq = fmaxf(sqrtf(qv.x * qv.x + qv.y * qv.y), 1e-9f);
            const float nk = fmaxf(sqrtf(kv.x * kv.x + kv.y * kv.y), 1e-9f);
            s = (qv.x * kv.x + qv.y * kv.y) / (nq * nk);
        }
        float m = s;
        #pragma unroll
        for (int d = 1; d < 16; d <<= 1) m = fmaxf(m, __shfl_xor(m, d));
        const float ex = __expf(s - m);
        float sum = ex;
        #pragma unroll
        for (int d = 1; d < 16; d <<= 1) sum += __shfl_xor(sum, d);
        aA[g] = ex / sum;
    }

    // ---- gather/accumulate: double buffer; U rows are 128 B fp8 (uint2/lane), V fp16 (uint4/lane) ----
    const uint2* Uv = (const uint2*)U8;
    const uint4* Vv = (const uint4*)Vh;
    char* accb = (char*)accs;

    uint2 ub[2][4];
    U4 vb[2];
    vb[0].u = Vv[(long)nodeBase * 16 + c16];
    #pragma unroll
    for (int ee = 0; ee < 4; ++ee) {
        const long je = __shfl(jA[0], 4 * ee + quarter);
        ub[0][ee] = Uv[je * 16 + c16];
    }

    #pragma unroll
    for (int g = 0; g < 8; ++g) {
        const int cur = g & 1, nx = cur ^ 1;
        if (g < 7) {
            vb[nx].u = Vv[(long)(nodeBase + g + 1) * 16 + c16];
            #pragma unroll
            for (int ee = 0; ee < 4; ++ee) {
                const long je = __shfl(jA[g + 1], 4 * ee + quarter);
                ub[nx][ee] = Uv[je * 16 + c16];
            }
        }
        const h2v z2 = {0, 0};
        h2v r0 = {0, 0}, r1 = {0, 0}, r2 = {0, 0}, r3 = {0, 0};
        #pragma unroll
        for (int ee = 0; ee < 4; ++ee) {
            const float ae = __shfl(aA[g], 4 * ee + quarter);
            const h2v az = pk2h(ae, ae);
            const uint2 uu = ub[cur][ee];
            auto q01 = __builtin_amdgcn_cvt_pk_f32_fp8(uu.x, false);
            auto q23 = __builtin_amdgcn_cvt_pk_f32_fp8(uu.x, true);
            auto q45 = __builtin_amdgcn_cvt_pk_f32_fp8(uu.y, false);
            auto q67 = __builtin_amdgcn_cvt_pk_f32_fp8(uu.y, true);
            const h2v u0 = pk2h(q01[0], q01[1]);
            const h2v u1 = pk2h(q23[0], q23[1]);
            const h2v u2 = pk2h(q45[0], q45[1]);
            const h2v u3 = pk2h(q67[0], q67[1]);
            r0 += __builtin_elementwise_max(u0 + vb[cur].h[0], z2) * az;
            r1 += __builtin_elementwise_max(u1 + vb[cur].h[1], z2) * az;
            r2 += __builtin_elementwise_max(u2 + vb[cur].h[2], z2) * az;
            r3 += __builtin_elementwise_max(u3 + vb[cur].h[3], z2) * az;
        }
        // reduce across the 4 quarter-groups
        h2v rr[4] = {r0, r1, r2, r3};
        #pragma unroll
        for (int p = 0; p < 4; ++p) {
            U1 v; v.h = rr[p];
            U1 o; o.i = __shfl_xor(v.i, 16); v.h = v.h + o.h;
            o.i = __shfl_xor(v.i, 32);       v.h = v.h + o.h;
            rr[p] = v.h;
        }
        if (quarter == 0) {
            const int rrow = wave * 8 + g;
            U4 pk; pk.h[0] = rr[0]; pk.h[1] = rr[1]; pk.h[2] = rr[2]; pk.h[3] = rr[3];
            *(uint4*)(accb + ((rrow * 256 + c16 * 16) ^ ((rrow & 7) << 4))) = pk.u;
        }
    }
    __syncthreads();

    // ---- swapped MFMA epilogue: D[64 W2cols][32 nodes] = W2'^T x ACC^T (both K-permuted) ----
    f16x8 waf[4];
    #pragma unroll
    for (int kb = 0; kb < 4; ++kb)
        waf[kb] = *(const f16x8*)&W2A[((wave * 4 + kb) * 64 + lane) * 8];
    const float4 b2v = *(const float4*)&b2[16 * wave + quarter * 4];

    f32x4 d[2];
    #pragma unroll
    for (int nt = 0; nt < 2; ++nt) d[nt] = (f32x4){0.f, 0.f, 0.f, 0.f};
    #pragma unroll
    for (int nt = 0; nt < 2; ++nt) {
        const int n = 16 * nt + c16;
        const int sw = (n & 7) << 4;
        #pragma unroll
        for (int kb = 0; kb < 4; ++kb) {
            const f16x8 bfr = *(const f16x8*)(accb + ((n * 256 + kb * 64 + quarter * 16) ^ sw));
            d[nt] = __builtin_amdgcn_mfma_f32_16x16x32_f16(waf[kb], bfr, d[nt], 0, 0, 0);
        }
    }
    #pragma unroll
    for (int nt = 0; nt < 2; ++nt) {
        const long node = blockIdx.x * 32 + 16 * nt + c16;
        const int col = 16 * wave + quarter * 4;
        float4 o;
        o.x = d[nt][0] + b2v.x; o.y = d[nt][1] + b2v.y;
        o.z = d[nt][2] + b2v.z; o.w = d[nt][3] + b2v.w;
        *(float4*)&out[node * 64 + col] = o;
    }
}

extern "C" void kernel_launch(void* const* d_in, const int* in_sizes, int n_in,
                              void* d_out, int out_size, void* d_ws, size_t ws_size,
                              hipStream_t stream) {
    const float* y   = (const float*)d_in[0];
    const int*   idx = (const int*)d_in[1];
    // d_in[2] = indptr: uniform DEG=16, unused
    const float* W1  = (const float*)d_in[3];
    const float* b1  = (const float*)d_in[4];
    const float* W2  = (const float*)d_in[5];
    const float* b2  = (const float*)d_in[6];
    float* out = (float*)d_out;

    char* ws = (char*)d_ws;
    unsigned char* U8 = (unsigned char*)ws;                // 12,800,000 B (fp8 e4m3)
    f16* Vh  = (f16*)(ws + 12800000);                      // 25,600,000 B (fp16, +b1)
    f16* W1A = (f16*)(ws + 38400000);                      // 32,768 B
    f16* W2A = (f16*)(ws + 38432768);                      // 16,384 B
    const size_t qn_off = 38449152;
    const bool useQN = (ws_size >= qn_off + (size_t)NNODE * sizeof(float2));
    float2* QN = useQN ? (float2*)(ws + qn_off) : nullptr;

    k_prep<<<24, 256, 0, stream>>>(W1, W2, W1A, W2A);
    k_uv<<<NT64, 256, 0, stream>>>(y, W1A, b1, U8, Vh, QN);
    if (useQN)
        k_agg<true><<<NTILE, 256, 0, stream>>>(y, idx, U8, Vh, QN, W2A, b2, out);
    else
        k_agg<false><<<NTILE, 256, 0, stream>>>(y, idx, U8, Vh, nullptr, W2A, b2, out);
}